// Round 2
// baseline (1139.199 us; speedup 1.0000x reference)
//
#include <hip/hip_runtime.h>
#include <hip/hip_bf16.h>

typedef _Float16 hh4 __attribute__((ext_vector_type(4)));
typedef _Float16 hh8 __attribute__((ext_vector_type(8)));
typedef float fx4 __attribute__((ext_vector_type(4)));

#define D_DIM 256
#define N_DIM 512
#define BM 64
#define STRIDE_Q 264   // 256 + 8 halves pad
#define STRIDE_P 520   // 512 + 8 halves pad

// ---------------------------------------------------------------------------
// Prep: normalize emb rows -> bankn (fp16, [N][D]); raw emb transposed ->
// embT (fp16, [D][N]). 8 blocks x 256 threads, 4 lanes per row.
// ---------------------------------------------------------------------------
__global__ void prep_kernel(const float* __restrict__ emb,
                            _Float16* __restrict__ bankn,
                            _Float16* __restrict__ embT) {
  const int tid = threadIdx.x;
  const int rl = tid >> 2;          // 0..63 row within block
  const int sub = tid & 3;          // 4 lanes per row
  const int row = blockIdx.x * 64 + rl;   // 0..511

  const float4* src = reinterpret_cast<const float4*>(emb + (size_t)row * D_DIM);
  float4 v[16];
  float ss = 0.f;
#pragma unroll
  for (int i = 0; i < 16; ++i) {
    v[i] = src[i * 4 + sub];        // element k = i*16 + sub*4
    ss += v[i].x * v[i].x + v[i].y * v[i].y + v[i].z * v[i].z + v[i].w * v[i].w;
  }
  ss += __shfl_xor(ss, 1);
  ss += __shfl_xor(ss, 2);
  const float inv = rsqrtf(fmaxf(ss, 1e-24f));

#pragma unroll
  for (int i = 0; i < 16; ++i) {
    const int k = i * 16 + sub * 4;
    hh4 h;
    h.x = (_Float16)(v[i].x * inv);
    h.y = (_Float16)(v[i].y * inv);
    h.z = (_Float16)(v[i].z * inv);
    h.w = (_Float16)(v[i].w * inv);
    *reinterpret_cast<hh4*>(&bankn[(size_t)row * D_DIM + k]) = h;
    // raw (un-normalized) emb, transposed for GEMM2 A-fragments
    embT[(size_t)(k + 0) * N_DIM + row] = (_Float16)v[i].x;
    embT[(size_t)(k + 1) * N_DIM + row] = (_Float16)v[i].y;
    embT[(size_t)(k + 2) * N_DIM + row] = (_Float16)v[i].z;
    embT[(size_t)(k + 3) * N_DIM + row] = (_Float16)v[i].w;
  }
}

// ---------------------------------------------------------------------------
// Fused, transposed-output version. 64 queries per workgroup, 8 waves.
// GEMM1 computes simT = bankn @ qn^T  (wave w owns n in [64w, 64w+64))
//   -> C layout: lane(q4,ln) holds sim[n = nb + q4*4 + r][m = mb + ln]
//   -> softmax over n needs only shfl_xor(16/32) + cross-wave LDS scratch
//   -> p written as coalesced float4 (4 consecutive n per lane)
// GEMM2 computes vecT = embT @ p^T  (wave w owns d in [32w, 32w+32))
//   -> vec written as coalesced float4 (4 consecutive d per lane)
// ---------------------------------------------------------------------------
__global__ __launch_bounds__(512, 4) void fused_kernel(
    const float* __restrict__ query,
    const _Float16* __restrict__ bankn,
    const _Float16* __restrict__ embT,
    float* __restrict__ out_vec,
    float* __restrict__ out_p) {
  __shared__ __align__(16) _Float16 smem[BM * STRIDE_P];  // qn (stride 264) then p (stride 520)
  __shared__ float scratch[2 * BM * 8];                   // [0..511] row-max, [512..1023] row-sum

  const int tid = threadIdx.x;
  const size_t b0 = (size_t)blockIdx.x * BM;

  // ---- Phase 0: load + l2-normalize 64 query rows -> smem fp16 ----
  {
    const int rl = tid >> 3;        // 0..63 row
    const int sub = tid & 7;        // 8 lanes per row
    const float4* src = reinterpret_cast<const float4*>(query + (b0 + rl) * D_DIM);
    float4 v[8];
    float ss = 0.f;
#pragma unroll
    for (int i = 0; i < 8; ++i) {
      v[i] = src[i * 8 + sub];
      ss += v[i].x * v[i].x + v[i].y * v[i].y + v[i].z * v[i].z + v[i].w * v[i].w;
    }
    ss += __shfl_xor(ss, 1);
    ss += __shfl_xor(ss, 2);
    ss += __shfl_xor(ss, 4);
    const float inv = rsqrtf(fmaxf(ss, 1e-24f));
#pragma unroll
    for (int i = 0; i < 8; ++i) {
      const int k = (i * 8 + sub) * 4;
      hh4 h;
      h.x = (_Float16)(v[i].x * inv);
      h.y = (_Float16)(v[i].y * inv);
      h.z = (_Float16)(v[i].z * inv);
      h.w = (_Float16)(v[i].w * inv);
      *reinterpret_cast<hh4*>(&smem[rl * STRIDE_Q + k]) = h;
    }
  }
  __syncthreads();

  const int wave = tid >> 6;  // 0..7
  const int lane = tid & 63;
  const int q4 = lane >> 4;   // k-group for A/B frags; row-group for C
  const int ln = lane & 15;   // A row (n or d) / B row (m) / C col (m)

  // ---- Phase 1: GEMM1  simT[64w..64w+64)[0..64), K=256 ----
  fx4 acc[4][4];  // [nt][mt]
#pragma unroll
  for (int nt = 0; nt < 4; ++nt)
#pragma unroll
    for (int mt = 0; mt < 4; ++mt) acc[nt][mt] = 0;

#pragma unroll 1
  for (int kk = 0; kk < 8; ++kk) {
    hh8 a[4], b[4];
#pragma unroll
    for (int nt = 0; nt < 4; ++nt)
      a[nt] = *reinterpret_cast<const hh8*>(
          &bankn[(size_t)(64 * wave + nt * 16 + ln) * D_DIM + kk * 32 + q4 * 8]);
#pragma unroll
    for (int mt = 0; mt < 4; ++mt)
      b[mt] = *reinterpret_cast<const hh8*>(&smem[(mt * 16 + ln) * STRIDE_Q + kk * 32 + q4 * 8]);
#pragma unroll
    for (int nt = 0; nt < 4; ++nt)
#pragma unroll
      for (int mt = 0; mt < 4; ++mt)
        acc[nt][mt] = __builtin_amdgcn_mfma_f32_16x16x32_f16(a[nt], b[mt], acc[nt][mt], 0, 0, 0);
  }

  // ---- Phase 2: softmax over n (rows of simT) per query column m ----
  // lane holds n = 64*wave + nt*16 + q4*4 + r, m = mt*16 + ln
  float pm[4];
#pragma unroll
  for (int mt = 0; mt < 4; ++mt) {
    float m = acc[0][mt][0];
#pragma unroll
    for (int nt = 0; nt < 4; ++nt)
#pragma unroll
      for (int r = 0; r < 4; ++r) m = fmaxf(m, acc[nt][mt][r]);
    m = fmaxf(m, __shfl_xor(m, 16));
    m = fmaxf(m, __shfl_xor(m, 32));
    pm[mt] = m;
  }
  if (q4 == 0) {
#pragma unroll
    for (int mt = 0; mt < 4; ++mt) scratch[(mt * 16 + ln) * 8 + wave] = pm[mt];
  }
  __syncthreads();

  float gm[4];
#pragma unroll
  for (int mt = 0; mt < 4; ++mt) {
    const int mi = mt * 16 + ln;
    const float g01 = fmaxf(scratch[mi * 8 + 0], scratch[mi * 8 + 1]);
    const float g23 = fmaxf(scratch[mi * 8 + 2], scratch[mi * 8 + 3]);
    const float g45 = fmaxf(scratch[mi * 8 + 4], scratch[mi * 8 + 5]);
    const float g67 = fmaxf(scratch[mi * 8 + 6], scratch[mi * 8 + 7]);
    gm[mt] = fmaxf(fmaxf(g01, g23), fmaxf(g45, g67));
  }

  float ps[4];
#pragma unroll
  for (int mt = 0; mt < 4; ++mt) {
    float s = 0.f;
#pragma unroll
    for (int nt = 0; nt < 4; ++nt)
#pragma unroll
      for (int r = 0; r < 4; ++r) {
        const float e = __expf(acc[nt][mt][r] - gm[mt]);
        acc[nt][mt][r] = e;
        s += e;
      }
    s += __shfl_xor(s, 16);
    s += __shfl_xor(s, 32);
    ps[mt] = s;
  }
  if (q4 == 0) {
#pragma unroll
    for (int mt = 0; mt < 4; ++mt) scratch[512 + (mt * 16 + ln) * 8 + wave] = ps[mt];
  }
  __syncthreads();

  // ---- finalize p: coalesced fp32 float4 to global, fp16 hh4 to smem ----
#pragma unroll
  for (int mt = 0; mt < 4; ++mt) {
    const int mi = mt * 16 + ln;
    float S = (scratch[512 + mi * 8 + 0] + scratch[512 + mi * 8 + 1]) +
              (scratch[512 + mi * 8 + 2] + scratch[512 + mi * 8 + 3]) +
              (scratch[512 + mi * 8 + 4] + scratch[512 + mi * 8 + 5]) +
              (scratch[512 + mi * 8 + 6] + scratch[512 + mi * 8 + 7]);
    const float invS = 1.0f / S;
#pragma unroll
    for (int nt = 0; nt < 4; ++nt) {
      fx4 pv;
#pragma unroll
      for (int r = 0; r < 4; ++r) pv[r] = acc[nt][mt][r] * invS;
      const int ncol = 64 * wave + nt * 16 + q4 * 4;
      *reinterpret_cast<fx4*>(&out_p[(b0 + mi) * N_DIM + ncol]) = pv;
      hh4 hp;
      hp.x = (_Float16)pv[0];
      hp.y = (_Float16)pv[1];
      hp.z = (_Float16)pv[2];
      hp.w = (_Float16)pv[3];
      *reinterpret_cast<hh4*>(&smem[mi * STRIDE_P + ncol]) = hp;
    }
  }
  __syncthreads();

  // ---- Phase 3: GEMM2  vecT[32w..32w+32)[0..64), K=512 ----
  fx4 acc2[2][4];  // [dt][mt]
#pragma unroll
  for (int dt = 0; dt < 2; ++dt)
#pragma unroll
    for (int mt = 0; mt < 4; ++mt) acc2[dt][mt] = 0;

#pragma unroll 1
  for (int kk = 0; kk < 16; ++kk) {
    hh8 e[2], pa[4];
#pragma unroll
    for (int dt = 0; dt < 2; ++dt)
      e[dt] = *reinterpret_cast<const hh8*>(
          &embT[(size_t)(32 * wave + dt * 16 + ln) * N_DIM + kk * 32 + q4 * 8]);
#pragma unroll
    for (int mt = 0; mt < 4; ++mt)
      pa[mt] = *reinterpret_cast<const hh8*>(&smem[(mt * 16 + ln) * STRIDE_P + kk * 32 + q4 * 8]);
#pragma unroll
    for (int dt = 0; dt < 2; ++dt)
#pragma unroll
      for (int mt = 0; mt < 4; ++mt)
        acc2[dt][mt] = __builtin_amdgcn_mfma_f32_16x16x32_f16(e[dt], pa[mt], acc2[dt][mt], 0, 0, 0);
  }

  // vec store: lane holds d = 32*wave + dt*16 + q4*4 + r, m = mt*16 + ln
#pragma unroll
  for (int mt = 0; mt < 4; ++mt) {
    const size_t vrow = (b0 + mt * 16 + ln) * D_DIM;
#pragma unroll
    for (int dt = 0; dt < 2; ++dt) {
      const int dcol = 32 * wave + dt * 16 + q4 * 4;
      *reinterpret_cast<fx4*>(&out_vec[vrow + dcol]) = acc2[dt][mt];
    }
  }
}

extern "C" void kernel_launch(void* const* d_in, const int* in_sizes, int n_in,
                              void* d_out, int out_size, void* d_ws, size_t ws_size,
                              hipStream_t stream) {
  const float* query = (const float*)d_in[0];
  const float* emb = (const float*)d_in[1];
  const int B = in_sizes[0] / D_DIM;  // 262144

  float* out_vec = (float*)d_out;                      // (B, 256) first
  float* out_p = out_vec + (size_t)B * D_DIM;          // then (B, 512)

  _Float16* bankn = (_Float16*)d_ws;                   // [N][D] fp16, normalized
  _Float16* embT = bankn + (size_t)N_DIM * D_DIM;      // [D][N] fp16, raw transposed

  prep_kernel<<<8, 256, 0, stream>>>(emb, bankn, embT);
  fused_kernel<<<B / BM, 512, 0, stream>>>(query, bankn, embT, out_vec, out_p);
}